// Round 2
// baseline (433.466 us; speedup 1.0000x reference)
//
#include <hip/hip_runtime.h>
#include <hip/hip_bf16.h>

#define NA   65536
#define DIN  512
#define DOUT 512
#define NE   8
#define NS   64
#define BM   128
#define BN   128
#define BK   32
#define TPS  16     // row-tiles per system: covers up to 2048 atoms (mean 1024, sd ~32)

typedef __attribute__((ext_vector_type(8))) __bf16 bf16x8;
typedef __attribute__((ext_vector_type(4))) float floatx4;

__device__ __forceinline__ void async_load16(const void* g, void* l) {
  __builtin_amdgcn_global_load_lds(
      (__attribute__((address_space(1))) void*)(void*)g,
      (__attribute__((address_space(3))) void*)l,
      16, 0, 0);
}

__global__ void init_kernel(int* counts) {
  int t = threadIdx.x;
  if (t < NS) counts[t] = 0;
}

__global__ void count_kernel(const int* __restrict__ bidx,
                             int* __restrict__ counts) {
  __shared__ int hist[NS];
  int t = threadIdx.x;
  if (t < NS) hist[t] = 0;
  __syncthreads();
  int s = bidx[blockIdx.x * 256 + t];
  atomicAdd(&hist[s], 1);
  __syncthreads();
  if (t < NS && hist[t] > 0) atomicAdd(&counts[t], hist[t]);
}

__global__ void scan_kernel(const int* __restrict__ counts,
                            int* __restrict__ starts,
                            int* __restrict__ cursors) {
  if (threadIdx.x == 0) {
    int run = 0;
    for (int s = 0; s < NS; s++) {
      starts[s] = run;
      cursors[s] = run;
      run += counts[s];
    }
  }
}

__global__ void scatter_kernel(const int* __restrict__ bidx,
                               int* __restrict__ cursors,
                               int* __restrict__ perm) {
  __shared__ int hist[NS];
  __shared__ int base[NS];
  int t = threadIdx.x;
  if (t < NS) hist[t] = 0;
  __syncthreads();
  int n = blockIdx.x * 256 + t;
  int s = bidx[n];
  int rank = atomicAdd(&hist[s], 1);
  __syncthreads();
  if (t < NS && hist[t] > 0) base[t] = atomicAdd(&cursors[t], hist[t]);
  __syncthreads();
  perm[base[s] + rank] = n;
}

// mixedW[s][o][i] = sum_e coeff[s][e] * W[e][o][i], bf16, K(i)-contiguous.
// grid (128, 8): block caches a 2048-float chunk of all 8 experts in regs,
// reuses across 8 systems. 1024 blocks -> 4 blocks/CU for latency hiding.
__global__ void mixw_kernel(const float* __restrict__ W,
                            const float* __restrict__ coeff,
                            ushort* __restrict__ mixedW) {
  int t = threadIdx.x;
  int base = blockIdx.x * 2048 + t * 8;
  float w[NE][8];
#pragma unroll
  for (int e = 0; e < NE; e++) {
    const float4* p = (const float4*)(W + e * (DOUT * DIN) + base);
    float4 a = p[0], b = p[1];
    w[e][0] = a.x; w[e][1] = a.y; w[e][2] = a.z; w[e][3] = a.w;
    w[e][4] = b.x; w[e][5] = b.y; w[e][6] = b.z; w[e][7] = b.w;
  }
  int s0 = blockIdx.y * 8;
  for (int si = 0; si < 8; si++) {
    int s = s0 + si;
    float o[8] = {0, 0, 0, 0, 0, 0, 0, 0};
#pragma unroll
    for (int e = 0; e < NE; e++) {
      float c = coeff[s * NE + e];
#pragma unroll
      for (int j = 0; j < 8; j++) o[j] += c * w[e][j];
    }
    union { bf16x8 v; uint4 u; } cv;
#pragma unroll
    for (int j = 0; j < 8; j++) cv.v[j] = (__bf16)o[j];
    *(uint4*)(mixedW + (size_t)s * (DOUT * DIN) + base) = cv.u;
  }
}

// Grouped GEMM: out[perm[r]][o] = sum_i x[perm[r]][i]*mixedW[s][o][i] + bias[o]
// 128x128xBK32, 4 waves (2x2), 4x4 of 16x16x32 bf16 MFMA per wave.
// A (fp32 x, row-gathered) and B (bf16) both staged via global_load_lds w=16
// into CHUNK-TRANSPOSED LDS: chunk c (16B) of row r lives at flat (c*128+r)*16.
// -> fragment ds_read_b128 hits consecutive 16B across lanes (2-way, free).
// fp32->bf16 convert happens after ds_read, per fragment (VALU co-issues).
__global__ __launch_bounds__(256) void gemm_kernel(
    const float* __restrict__ x, const ushort* __restrict__ mixedW,
    const int* __restrict__ perm, const int* __restrict__ starts,
    const int* __restrict__ counts, const float* __restrict__ bias,
    float* __restrict__ out) {
  int st = blockIdx.y;          // system*16 + rowtile
  int s = st >> 4;
  int tt = st & 15;
  int count = counts[s];
  int r0 = tt * BM;
  if (r0 >= count) return;
  int rows = min(BM, count - r0);
  int n0 = blockIdx.x * BN;
  int base = starts[s] + r0;

  __shared__ __align__(16) float  Alds[BM * BK];   // 16KB chunk-transposed fp32
  __shared__ __align__(16) ushort Blds[BN * BK];   // 8KB  chunk-transposed bf16
  __shared__ int prow[BM];

  int tid = threadIdx.x;
  int lane = tid & 63;
  int wave = tid >> 6;

  if (tid < BM) prow[tid] = perm[base + min(tid, rows - 1)];
  __syncthreads();

  // A async: 4 rounds j; L=j*256+tid; row=L&127; c=L>>7 (8 chunks of 4 floats)
  const float* aptr[4];
#pragma unroll
  for (int j = 0; j < 4; j++) {
    int L = j * 256 + tid;
    int row = L & 127, c = L >> 7;
    aptr[j] = x + (size_t)prow[row] * DIN + c * 4;
  }
  // B async: 2 rounds; col=L&127; c=L>>7 (4 chunks of 8 bf16)
  const ushort* bptr[2];
#pragma unroll
  for (int j = 0; j < 2; j++) {
    int L = j * 256 + tid;
    int col = L & 127, c = L >> 7;
    bptr[j] = mixedW + (size_t)s * (DOUT * DIN) + (size_t)(n0 + col) * DIN + c * 8;
  }

  floatx4 acc[4][4];
#pragma unroll
  for (int mt = 0; mt < 4; mt++)
#pragma unroll
    for (int nt = 0; nt < 4; nt++) acc[mt][nt] = {0.f, 0.f, 0.f, 0.f};

  int wm = wave >> 1, wn = wave & 1;
  int m15 = lane & 15, quad = lane >> 4;

  for (int kk = 0; kk < DIN; kk += BK) {
#pragma unroll
    for (int j = 0; j < 4; j++)
      async_load16(aptr[j] + kk, (char*)Alds + j * 4096 + wave * 1024);
#pragma unroll
    for (int j = 0; j < 2; j++)
      async_load16(bptr[j] + kk, (char*)Blds + j * 4096 + wave * 1024);
    __syncthreads();

    bf16x8 af[4], bfm[4];
#pragma unroll
    for (int i = 0; i < 4; i++) {
      int row = wm * 64 + i * 16 + m15;
      floatx4 lo = *(const floatx4*)(Alds + (2 * quad) * 512 + row * 4);
      floatx4 hi = *(const floatx4*)(Alds + (2 * quad + 1) * 512 + row * 4);
      bf16x8 h;
      h[0] = (__bf16)lo[0]; h[1] = (__bf16)lo[1];
      h[2] = (__bf16)lo[2]; h[3] = (__bf16)lo[3];
      h[4] = (__bf16)hi[0]; h[5] = (__bf16)hi[1];
      h[6] = (__bf16)hi[2]; h[7] = (__bf16)hi[3];
      af[i] = h;
      int col = wn * 64 + i * 16 + m15;
      bfm[i] = *(const bf16x8*)(Blds + quad * 1024 + col * 8);
    }
#pragma unroll
    for (int mt = 0; mt < 4; mt++)
#pragma unroll
      for (int nt = 0; nt < 4; nt++)
        acc[mt][nt] = __builtin_amdgcn_mfma_f32_16x16x32_bf16(
            af[mt], bfm[nt], acc[mt][nt], 0, 0, 0);
    __syncthreads();
  }

  float bv[4];
#pragma unroll
  for (int nt = 0; nt < 4; nt++) bv[nt] = bias[n0 + wn * 64 + nt * 16 + m15];

#pragma unroll
  for (int mt = 0; mt < 4; mt++) {
    int rb = wm * 64 + mt * 16 + quad * 4;
    int pr[4];
#pragma unroll
    for (int r = 0; r < 4; r++) pr[r] = prow[rb + r];
#pragma unroll
    for (int nt = 0; nt < 4; nt++) {
      int col = n0 + wn * 64 + nt * 16 + m15;
#pragma unroll
      for (int r = 0; r < 4; r++) {
        if (rb + r < rows)
          out[(size_t)pr[r] * DOUT + col] = acc[mt][nt][r] + bv[nt];
      }
    }
  }
}

extern "C" void kernel_launch(void* const* d_in, const int* in_sizes, int n_in,
                              void* d_out, int out_size, void* d_ws,
                              size_t ws_size, hipStream_t stream) {
  const float* x     = (const float*)d_in[0];
  const float* coeff = (const float*)d_in[1];
  const int*   bidx  = (const int*)d_in[2];
  const float* W     = (const float*)d_in[3];
  const float* bias  = (const float*)d_in[4];
  float* out = (float*)d_out;

  char* ws = (char*)d_ws;
  int* counts  = (int*)ws;            // 64 ints
  int* starts  = (int*)(ws + 256);    // 64 ints
  int* cursors = (int*)(ws + 512);    // 64 ints
  int* perm    = (int*)(ws + 1024);   // 256 KB
  ushort* mixedW = (ushort*)(ws + 1024 + NA * sizeof(int));  // 33.5 MB

  hipLaunchKernelGGL(init_kernel, dim3(1), dim3(64), 0, stream, counts);
  hipLaunchKernelGGL(count_kernel, dim3(NA / 256), dim3(256), 0, stream,
                     bidx, counts);
  hipLaunchKernelGGL(scan_kernel, dim3(1), dim3(64), 0, stream,
                     counts, starts, cursors);
  hipLaunchKernelGGL(scatter_kernel, dim3(NA / 256), dim3(256), 0, stream,
                     bidx, cursors, perm);
  hipLaunchKernelGGL(mixw_kernel, dim3(DOUT * DIN / 2048, 8), dim3(256), 0,
                     stream, W, coeff, mixedW);
  hipLaunchKernelGGL(gemm_kernel, dim3(DOUT / BN, NS * TPS), dim3(256), 0,
                     stream, x, mixedW, perm, starts, counts, bias, out);
}